// Round 6
// baseline (732.011 us; speedup 1.0000x reference)
//
#include <hip/hip_runtime.h>
#include <hip/hip_bf16.h>
#include <math.h>

#define DD 64
#define BROWS 64            // rows per bucket
#define BSH 6               // log2(BROWS)
#define MAXB 1024           // max buckets supported
#define CAPB 1280           // fixed bucket capacity (mean 1024 + 8 sigma)
typedef unsigned long long u64;
typedef unsigned int u32;
typedef unsigned short u16;

// ---------------------------------------------------------------------------
// Linear: he = bf16( (x @ W^T) * artanh(||x||)/||x|| )  (exact telescoped
// logmap0(mobius_matvec(W,x,c=1))). 16 rows/block (4 waves x 4 rows) to cut
// the per-block W re-read 4x. Block 0 zeroes bucket cursors + spill counter
// (completes before hgcn_bin launches, stream order).
// ---------------------------------------------------------------------------
__global__ __launch_bounds__(256) void hgcn_linear(const float* __restrict__ x,
                                                   const float* __restrict__ W,
                                                   __hip_bfloat16* __restrict__ he,
                                                   int* __restrict__ bcur,
                                                   int* __restrict__ nspill,
                                                   int n) {
  if (blockIdx.x == 0) {
    for (int i = threadIdx.x; i < MAXB; i += 256) bcur[i] = 0;
    if (threadIdx.x == 0) nspill[0] = 0;
  }
  __shared__ float Wl[64][68];     // stride-68 + per-lane k-rotation: no 8-way conflicts
  __shared__ float xs[16][64];
  const int tid = threadIdx.x;
  for (int i = tid; i < 64 * 64; i += 256) Wl[i >> 6][i & 63] = W[i];
  const int wave = tid >> 6, lane = tid & 63;
  const int rbase = blockIdx.x * 16 + wave * 4;
  float xv[4];
  #pragma unroll
  for (int q = 0; q < 4; ++q) {
    const int row = rbase + q;
    xv[q] = (row < n) ? x[(size_t)row * DD + lane] : 0.f;
    xs[wave * 4 + q][lane] = xv[q];
  }
  __syncthreads();

  const int j0 = (lane >> 3) & 7;
  #pragma unroll
  for (int q = 0; q < 4; ++q) {
    const int row = rbase + q;
    if (row >= n) break;
    float nx2 = xv[q] * xv[q];
    #pragma unroll
    for (int m = 1; m < 64; m <<= 1) nx2 += __shfl_xor(nx2, m);
    const float nx = fmaxf(sqrtf(nx2), 1e-15f);
    const float s  = atanhf(fminf(nx, 1.f - 1e-7f)) / nx;
    float acc = 0.f;
    #pragma unroll
    for (int jj = 0; jj < 16; ++jj) {
      const int k = ((jj + j0) & 15) << 2;
      const float4 xk = *reinterpret_cast<const float4*>(&xs[wave * 4 + q][k]);
      const float4 wk = *reinterpret_cast<const float4*>(&Wl[lane][k]);
      acc = fmaf(xk.x, wk.x, acc);
      acc = fmaf(xk.y, wk.y, acc);
      acc = fmaf(xk.z, wk.z, acc);
      acc = fmaf(xk.w, wk.w, acc);
    }
    he[(size_t)row * DD + lane] = __float2bfloat16(acc * s);
  }
}

// ---------------------------------------------------------------------------
// Bin (single pass over edges): per-block LDS hist -> one contiguous run
// reservation per bucket (fixed base b*CAPB) -> near-coalesced writes.
// Edges beyond CAPB go to the spill list (cap = ne, fully safe; ~never).
// Packed edge: w:f32<<32 | rowLocal:6<<16 | col:16.  Spill: w<<32|rowGlobal:16<<16|col.
// ---------------------------------------------------------------------------
#define BINB 1024
#define BINC 6144
__global__ __launch_bounds__(1024) void hgcn_bin(const int* __restrict__ ei,
                                                 const float* __restrict__ ew,
                                                 int* __restrict__ bcur,
                                                 u64* __restrict__ stage,
                                                 u64* __restrict__ spill,
                                                 int* __restrict__ nspill,
                                                 int ne) {
  __shared__ int h[MAXB], cur[MAXB], gp[MAXB];
  const int tid = threadIdx.x;
  h[tid] = 0; cur[tid] = 0;
  __syncthreads();
  const int eb = blockIdx.x * BINC;
  const int m = min(BINC, ne - eb);
  for (int i = tid; i < m; i += BINB) atomicAdd(&h[ei[eb + i] >> BSH], 1);
  __syncthreads();
  gp[tid] = h[tid] ? atomicAdd(&bcur[tid], h[tid]) : 0;
  __syncthreads();
  for (int i = tid; i < m; i += BINB) {
    const int r = ei[eb + i];
    const int c = ei[ne + eb + i];
    const float w = ew[eb + i];
    const int b = r >> BSH;
    const int pos = gp[b] + atomicAdd(&cur[b], 1);
    if (pos < CAPB) {
      stage[(size_t)b * CAPB + pos] =
          ((u64)__float_as_uint(w) << 32) | ((u32)(r & (BROWS - 1)) << 16) | (u32)c;
    } else {
      const int sp = atomicAdd(nspill, 1);
      spill[sp] = ((u64)__float_as_uint(w) << 32) | ((u32)(r & 0xffff) << 16) | (u32)c;
    }
  }
}

// ---------------------------------------------------------------------------
// Bucket aggregate + fused epilogue (NO fp atomics): single-chunk LDS
// counting sort by local row (int ds_add cursors + ds_write_b64), then each
// 8-lane group register-accumulates its 2 rows; spill-scan (normally empty);
// out = proj(expmap0(relu(acc))), direct coalesced store.
// ---------------------------------------------------------------------------
__global__ __launch_bounds__(256) void hgcn_bagg(const u16* __restrict__ he,
                                                 const u64* __restrict__ stage,
                                                 const int* __restrict__ bcur,
                                                 const u64* __restrict__ spill,
                                                 const int* __restrict__ nspill,
                                                 float* __restrict__ out, int n) {
  __shared__ u64 ed[CAPB];
  __shared__ int lh[BROWS + 1];
  __shared__ int lcur[BROWS];
  const int t = threadIdx.x;
  const int b = blockIdx.x;
  const u64* sb = stage + (size_t)b * CAPB;
  const int cnt = min(bcur[b], CAPB);
  const int g = t >> 3, l = t & 7;          // 32 groups x 8 lanes
  const int r0 = 2 * g, r1 = 2 * g + 1;
  float a0[8] = {0.f, 0.f, 0.f, 0.f, 0.f, 0.f, 0.f, 0.f};
  float a1[8] = {0.f, 0.f, 0.f, 0.f, 0.f, 0.f, 0.f, 0.f};

  if (t < BROWS) lcur[t] = 0;
  __syncthreads();
  for (int i = t; i < cnt; i += 256)
    atomicAdd(&lcur[(int)((sb[i] >> 16) & (BROWS - 1))], 1);
  __syncthreads();
  if (t < 64) {
    const int v = lcur[t];
    int sc = v;
    #pragma unroll
    for (int d = 1; d < 64; d <<= 1) {
      const int u = __shfl_up(sc, d);
      if (t >= d) sc += u;
    }
    lh[t] = sc - v;
    lcur[t] = sc - v;
    if (t == 63) lh[64] = sc;
  }
  __syncthreads();
  for (int i = t; i < cnt; i += 256) {
    const u64 p = sb[i];
    const int rl = (int)((p >> 16) & (BROWS - 1));
    const int pos = atomicAdd(&lcur[rl], 1);
    ed[pos] = p;
  }
  __syncthreads();

  for (int j = lh[r0]; j < lh[r0 + 1]; ++j) {
    const u64 p = ed[j];
    const int col = (int)(p & 0xffffu);
    const float w = __uint_as_float((u32)(p >> 32));
    const uint4 q = reinterpret_cast<const uint4*>(he + ((size_t)col << 6))[l];
    a0[0] = fmaf(w, __uint_as_float(q.x << 16), a0[0]);
    a0[1] = fmaf(w, __uint_as_float(q.x & 0xffff0000u), a0[1]);
    a0[2] = fmaf(w, __uint_as_float(q.y << 16), a0[2]);
    a0[3] = fmaf(w, __uint_as_float(q.y & 0xffff0000u), a0[3]);
    a0[4] = fmaf(w, __uint_as_float(q.z << 16), a0[4]);
    a0[5] = fmaf(w, __uint_as_float(q.z & 0xffff0000u), a0[5]);
    a0[6] = fmaf(w, __uint_as_float(q.w << 16), a0[6]);
    a0[7] = fmaf(w, __uint_as_float(q.w & 0xffff0000u), a0[7]);
  }
  for (int j = lh[r1]; j < lh[r1 + 1]; ++j) {
    const u64 p = ed[j];
    const int col = (int)(p & 0xffffu);
    const float w = __uint_as_float((u32)(p >> 32));
    const uint4 q = reinterpret_cast<const uint4*>(he + ((size_t)col << 6))[l];
    a1[0] = fmaf(w, __uint_as_float(q.x << 16), a1[0]);
    a1[1] = fmaf(w, __uint_as_float(q.x & 0xffff0000u), a1[1]);
    a1[2] = fmaf(w, __uint_as_float(q.y << 16), a1[2]);
    a1[3] = fmaf(w, __uint_as_float(q.y & 0xffff0000u), a1[3]);
    a1[4] = fmaf(w, __uint_as_float(q.z << 16), a1[4]);
    a1[5] = fmaf(w, __uint_as_float(q.z & 0xffff0000u), a1[5]);
    a1[6] = fmaf(w, __uint_as_float(q.w << 16), a1[6]);
    a1[7] = fmaf(w, __uint_as_float(q.w & 0xffff0000u), a1[7]);
  }

  // spill-scan: normally nspill == 0 -> one scalar load + skip.
  const int ns = nspill[0];
  for (int sidx = 0; sidx < ns; ++sidx) {
    const u64 p = spill[sidx];
    const int grow = (int)((p >> 16) & 0xffffu);
    if ((grow >> BSH) != b) continue;
    const int rl = grow & (BROWS - 1);
    if (rl != r0 && rl != r1) continue;
    const int col = (int)(p & 0xffffu);
    const float w = __uint_as_float((u32)(p >> 32));
    const uint4 q = reinterpret_cast<const uint4*>(he + ((size_t)col << 6))[l];
    float* a = (rl == r0) ? a0 : a1;
    a[0] = fmaf(w, __uint_as_float(q.x << 16), a[0]);
    a[1] = fmaf(w, __uint_as_float(q.x & 0xffff0000u), a[1]);
    a[2] = fmaf(w, __uint_as_float(q.y << 16), a[2]);
    a[3] = fmaf(w, __uint_as_float(q.y & 0xffff0000u), a[3]);
    a[4] = fmaf(w, __uint_as_float(q.z << 16), a[4]);
    a[5] = fmaf(w, __uint_as_float(q.z & 0xffff0000u), a[5]);
    a[6] = fmaf(w, __uint_as_float(q.w << 16), a[6]);
    a[7] = fmaf(w, __uint_as_float(q.w & 0xffff0000u), a[7]);
  }

  // epilogue: out = proj(expmap0(relu(acc)))  (8-lane group reduce)
  const float maxn = 1.0f - 4e-3f;
  {
    float ss = 0.f;
    #pragma unroll
    for (int k = 0; k < 8; ++k) { a0[k] = fmaxf(a0[k], 0.f); ss = fmaf(a0[k], a0[k], ss); }
    ss += __shfl_xor(ss, 1); ss += __shfl_xor(ss, 2); ss += __shfl_xor(ss, 4);
    const float nu = fmaxf(sqrtf(ss), 1e-15f);
    const float th = tanhf(nu);
    const float scale = (th > maxn) ? (maxn / nu) : (th / nu);
    const int grow = (b << BSH) + r0;
    if (grow < n) {
      float4* op = reinterpret_cast<float4*>(out + (size_t)grow * DD + (size_t)l * 8);
      op[0] = float4{a0[0] * scale, a0[1] * scale, a0[2] * scale, a0[3] * scale};
      op[1] = float4{a0[4] * scale, a0[5] * scale, a0[6] * scale, a0[7] * scale};
    }
  }
  {
    float ss = 0.f;
    #pragma unroll
    for (int k = 0; k < 8; ++k) { a1[k] = fmaxf(a1[k], 0.f); ss = fmaf(a1[k], a1[k], ss); }
    ss += __shfl_xor(ss, 1); ss += __shfl_xor(ss, 2); ss += __shfl_xor(ss, 4);
    const float nu = fmaxf(sqrtf(ss), 1e-15f);
    const float th = tanhf(nu);
    const float scale = (th > maxn) ? (maxn / nu) : (th / nu);
    const int grow = (b << BSH) + r1;
    if (grow < n) {
      float4* op = reinterpret_cast<float4*>(out + (size_t)grow * DD + (size_t)l * 8);
      op[0] = float4{a1[0] * scale, a1[1] * scale, a1[2] * scale, a1[3] * scale};
      op[1] = float4{a1[4] * scale, a1[5] * scale, a1[6] * scale, a1[7] * scale};
    }
  }
}

// ---------------------------------------------------------------------------
// Deep fallback (tiny ws): atomic scatter path, fp32.
// ---------------------------------------------------------------------------
__global__ __launch_bounds__(256) void hgcn_linf32(const float* __restrict__ x,
                                                   const float* __restrict__ W,
                                                   float* __restrict__ he, int n) {
  __shared__ float Wl[64][68];
  __shared__ float xs[4][64];
  const int tid = threadIdx.x;
  for (int i = tid; i < 64 * 64; i += 256) Wl[i >> 6][i & 63] = W[i];
  const int wave = tid >> 6, lane = tid & 63;
  const int row = blockIdx.x * 4 + wave;
  float xv = 0.f;
  if (row < n) xv = x[row * DD + lane];
  xs[wave][lane] = xv;
  __syncthreads();
  if (row >= n) return;
  float nx2 = xv * xv;
  #pragma unroll
  for (int m = 1; m < 64; m <<= 1) nx2 += __shfl_xor(nx2, m);
  const float nx = fmaxf(sqrtf(nx2), 1e-15f);
  const float s = atanhf(fminf(nx, 1.f - 1e-7f)) / nx;
  const int j0 = (lane >> 3) & 7;
  float acc = 0.f;
  #pragma unroll
  for (int jj = 0; jj < 16; ++jj) {
    const int k = ((jj + j0) & 15) << 2;
    const float4 xk = *reinterpret_cast<const float4*>(&xs[wave][k]);
    const float4 wk = *reinterpret_cast<const float4*>(&Wl[lane][k]);
    acc = fmaf(xk.x, wk.x, acc); acc = fmaf(xk.y, wk.y, acc);
    acc = fmaf(xk.z, wk.z, acc); acc = fmaf(xk.w, wk.w, acc);
  }
  he[row * DD + lane] = acc * s;
}

__global__ __launch_bounds__(256) void hgcn_zero(float* __restrict__ p, int n4) {
  const int i = blockIdx.x * 256 + threadIdx.x;
  if (i < n4) reinterpret_cast<float4*>(p)[i] = float4{0.f, 0.f, 0.f, 0.f};
}

__global__ __launch_bounds__(256) void hgcn_scatter(const float* __restrict__ he,
                                                    const int* __restrict__ ei,
                                                    const float* __restrict__ ew,
                                                    float* __restrict__ sup, int ne) {
  const int t = blockIdx.x * 256 + threadIdx.x;
  const int e = t >> 4, l = t & 15;
  if (e >= ne) return;
  const int row = ei[e];
  const int col = ei[ne + e];
  const float w = ew[e];
  const float4 v = *reinterpret_cast<const float4*>(he + (size_t)col * DD + l * 4);
  float* dst = sup + (size_t)row * DD + l * 4;
  unsafeAtomicAdd(dst + 0, w * v.x);
  unsafeAtomicAdd(dst + 1, w * v.y);
  unsafeAtomicAdd(dst + 2, w * v.z);
  unsafeAtomicAdd(dst + 3, w * v.w);
}

__global__ __launch_bounds__(256) void hgcn_final(const float* __restrict__ sup,
                                                  float* __restrict__ out, int n) {
  const int t = blockIdx.x * 256 + threadIdx.x;
  const int r = t >> 4, l = t & 15;
  if (r >= n) return;
  float4 v = *reinterpret_cast<const float4*>(sup + (size_t)r * DD + l * 4);
  v.x = fmaxf(v.x, 0.f); v.y = fmaxf(v.y, 0.f);
  v.z = fmaxf(v.z, 0.f); v.w = fmaxf(v.w, 0.f);
  float p = v.x*v.x + v.y*v.y + v.z*v.z + v.w*v.w;
  p += __shfl_xor(p, 1); p += __shfl_xor(p, 2);
  p += __shfl_xor(p, 4); p += __shfl_xor(p, 8);
  const float nu = fmaxf(sqrtf(p), 1e-15f);
  const float th = tanhf(nu);
  float scale = th / nu;
  const float maxn = 1.0f - 4e-3f;
  if (th > maxn) scale = maxn / nu;
  float4 o = {v.x*scale, v.y*scale, v.z*scale, v.w*scale};
  *reinterpret_cast<float4*>(out + (size_t)r * DD + l * 4) = o;
}

extern "C" void kernel_launch(void* const* d_in, const int* in_sizes, int n_in,
                              void* d_out, int out_size, void* d_ws, size_t ws_size,
                              hipStream_t stream) {
  const float* x  = (const float*)d_in[0];
  const float* W  = (const float*)d_in[1];
  const float* ew = (const float*)d_in[2];
  const int*   ei = (const int*)d_in[3];
  const int n  = in_sizes[0] / DD;          // 50000
  const int ne = in_sizes[2];               // 800000
  const int nb = (n + BROWS - 1) / BROWS;   // buckets (782)

  // ws layout (16B-aligned blocks)
  size_t off_he    = 0;
  size_t off_stage = off_he + (((size_t)n * DD * 2 + 15) / 16) * 16;
  size_t off_spill = off_stage + (size_t)MAXB * CAPB * 8;
  size_t off_bcur  = off_spill + (size_t)ne * 8;
  size_t off_nsp   = off_bcur + MAXB * 4;
  size_t need      = off_nsp + 64;

  // mean edges/bucket must leave the 8-sigma slack inside CAPB
  const bool capOK = ((size_t)ne / (size_t)nb) + 8 * 40 <= CAPB;

  if (ws_size >= need && n <= 65535 && nb <= MAXB && capOK) {
    __hip_bfloat16* he = (__hip_bfloat16*)((char*)d_ws + off_he);
    u64* stage  = (u64*)((char*)d_ws + off_stage);
    u64* spill  = (u64*)((char*)d_ws + off_spill);
    int* bcur   = (int*)((char*)d_ws + off_bcur);
    int* nspill = (int*)((char*)d_ws + off_nsp);
    float* out  = (float*)d_out;

    hipLaunchKernelGGL(hgcn_linear, dim3((n + 15) / 16),           dim3(256),  0, stream,
                       x, W, he, bcur, nspill, n);
    hipLaunchKernelGGL(hgcn_bin,    dim3((ne + BINC - 1) / BINC),  dim3(BINB), 0, stream,
                       ei, ew, bcur, stage, spill, nspill, ne);
    hipLaunchKernelGGL(hgcn_bagg,   dim3(nb),                      dim3(256),  0, stream,
                       (const u16*)he, stage, bcur, spill, nspill, out, n);
  } else {
    float* he  = (float*)d_out;
    float* sup = (float*)d_ws;
    float* out = (float*)d_out;
    const int n4 = n * DD / 4;
    hipLaunchKernelGGL(hgcn_zero,    dim3((n4 + 255) / 256),       dim3(256), 0, stream, sup, n4);
    hipLaunchKernelGGL(hgcn_linf32,  dim3((n + 3) / 4),            dim3(256), 0, stream, x, W, he, n);
    hipLaunchKernelGGL(hgcn_scatter, dim3((ne * 16 + 255) / 256),  dim3(256), 0, stream, he, ei, ew, sup, ne);
    hipLaunchKernelGGL(hgcn_final,   dim3((n * 16 + 255) / 256),   dim3(256), 0, stream, sup, out, n);
  }
}

// Round 7
// 78.029 us; speedup vs baseline: 9.3813x; 9.3813x over previous
//
#include <hip/hip_runtime.h>
#include <hip/hip_bf16.h>
#include <math.h>

#define DD 64
#define BROWS 64            // rows per bucket
#define BSH 6               // log2(BROWS)
#define MAXB 1024           // max buckets supported
#define CAPB 1536           // fixed bucket capacity (mean + >8 sigma headroom)
typedef unsigned long long u64;
typedef unsigned int u32;
typedef unsigned short u16;

// ---------------------------------------------------------------------------
// Linear: he = bf16( (x @ W^T) * artanh(||x||)/||x|| )  (exact telescoped
// logmap0(mobius_matvec(W,x,c=1))). 16 rows/block (4 waves x 4 rows) to cut
// the per-block W re-read 4x. Block 0 zeroes bucket cursors + spill counter
// (completes before hgcn_bin launches, stream order).
// ---------------------------------------------------------------------------
__global__ __launch_bounds__(256) void hgcn_linear(const float* __restrict__ x,
                                                   const float* __restrict__ W,
                                                   __hip_bfloat16* __restrict__ he,
                                                   int* __restrict__ bcur,
                                                   int* __restrict__ nspill,
                                                   int n) {
  if (blockIdx.x == 0) {
    for (int i = threadIdx.x; i < MAXB; i += 256) bcur[i] = 0;
    if (threadIdx.x == 0) nspill[0] = 0;
  }
  __shared__ float Wl[64][68];     // stride-68 + per-lane k-rotation: no 8-way conflicts
  __shared__ float xs[16][64];
  const int tid = threadIdx.x;
  for (int i = tid; i < 64 * 64; i += 256) Wl[i >> 6][i & 63] = W[i];
  const int wave = tid >> 6, lane = tid & 63;
  const int rbase = blockIdx.x * 16 + wave * 4;
  float xv[4];
  #pragma unroll
  for (int q = 0; q < 4; ++q) {
    const int row = rbase + q;
    xv[q] = (row < n) ? x[(size_t)row * DD + lane] : 0.f;
    xs[wave * 4 + q][lane] = xv[q];
  }
  __syncthreads();

  const int j0 = (lane >> 3) & 7;
  #pragma unroll
  for (int q = 0; q < 4; ++q) {
    const int row = rbase + q;
    if (row >= n) break;
    float nx2 = xv[q] * xv[q];
    #pragma unroll
    for (int m = 1; m < 64; m <<= 1) nx2 += __shfl_xor(nx2, m);
    const float nx = fmaxf(sqrtf(nx2), 1e-15f);
    const float s  = atanhf(fminf(nx, 1.f - 1e-7f)) / nx;
    float acc = 0.f;
    #pragma unroll
    for (int jj = 0; jj < 16; ++jj) {
      const int k = ((jj + j0) & 15) << 2;
      const float4 xk = *reinterpret_cast<const float4*>(&xs[wave * 4 + q][k]);
      const float4 wk = *reinterpret_cast<const float4*>(&Wl[lane][k]);
      acc = fmaf(xk.x, wk.x, acc);
      acc = fmaf(xk.y, wk.y, acc);
      acc = fmaf(xk.z, wk.z, acc);
      acc = fmaf(xk.w, wk.w, acc);
    }
    he[(size_t)row * DD + lane] = __float2bfloat16(acc * s);
  }
}

// ---------------------------------------------------------------------------
// Bin (single pass over edges): per-block LDS hist -> one contiguous run
// reservation per bucket (fixed base b*CAPB) -> near-coalesced writes.
// Edges beyond CAPB go to the spill list (cap = ne, fully safe; ~never hit).
// Packed edge: w:f32<<32 | rowLocal:6<<16 | col:16.  Spill: w<<32|rowGlobal:16<<16|col.
// ---------------------------------------------------------------------------
#define BINB 1024
#define BINC 6144
__global__ __launch_bounds__(1024) void hgcn_bin(const int* __restrict__ ei,
                                                 const float* __restrict__ ew,
                                                 int* __restrict__ bcur,
                                                 u64* __restrict__ stage,
                                                 u64* __restrict__ spill,
                                                 int* __restrict__ nspill,
                                                 int ne) {
  __shared__ int h[MAXB], cur[MAXB], gp[MAXB];
  const int tid = threadIdx.x;
  h[tid] = 0; cur[tid] = 0;
  __syncthreads();
  const int eb = blockIdx.x * BINC;
  const int m = min(BINC, ne - eb);
  for (int i = tid; i < m; i += BINB) atomicAdd(&h[ei[eb + i] >> BSH], 1);
  __syncthreads();
  gp[tid] = h[tid] ? atomicAdd(&bcur[tid], h[tid]) : 0;
  __syncthreads();
  for (int i = tid; i < m; i += BINB) {
    const int r = ei[eb + i];
    const int c = ei[ne + eb + i];
    const float w = ew[eb + i];
    const int b = r >> BSH;
    const int pos = gp[b] + atomicAdd(&cur[b], 1);
    if (pos < CAPB) {
      stage[(size_t)b * CAPB + pos] =
          ((u64)__float_as_uint(w) << 32) | ((u32)(r & (BROWS - 1)) << 16) | (u32)c;
    } else {
      const int sp = atomicAdd(nspill, 1);
      spill[sp] = ((u64)__float_as_uint(w) << 32) | ((u32)(r & 0xffff) << 16) | (u32)c;
    }
  }
}

// ---------------------------------------------------------------------------
// Bucket aggregate + fused epilogue (NO fp atomics): single-chunk LDS
// counting sort by local row (int ds_add cursors + ds_write_b64), then each
// 8-lane group register-accumulates its 2 rows; spill-scan (normally empty);
// out = proj(expmap0(relu(acc))), direct coalesced store.
// ---------------------------------------------------------------------------
__global__ __launch_bounds__(256) void hgcn_bagg(const u16* __restrict__ he,
                                                 const u64* __restrict__ stage,
                                                 const int* __restrict__ bcur,
                                                 const u64* __restrict__ spill,
                                                 const int* __restrict__ nspill,
                                                 float* __restrict__ out, int n) {
  __shared__ u64 ed[CAPB];
  __shared__ int lh[BROWS + 1];
  __shared__ int lcur[BROWS];
  const int t = threadIdx.x;
  const int b = blockIdx.x;
  const u64* sb = stage + (size_t)b * CAPB;
  const int cnt = min(bcur[b], CAPB);
  const int g = t >> 3, l = t & 7;          // 32 groups x 8 lanes
  const int r0 = 2 * g, r1 = 2 * g + 1;
  float a0[8] = {0.f, 0.f, 0.f, 0.f, 0.f, 0.f, 0.f, 0.f};
  float a1[8] = {0.f, 0.f, 0.f, 0.f, 0.f, 0.f, 0.f, 0.f};

  if (t < BROWS) lcur[t] = 0;
  __syncthreads();
  for (int i = t; i < cnt; i += 256)
    atomicAdd(&lcur[(int)((sb[i] >> 16) & (BROWS - 1))], 1);
  __syncthreads();
  if (t < 64) {
    const int v = lcur[t];
    int sc = v;
    #pragma unroll
    for (int d = 1; d < 64; d <<= 1) {
      const int u = __shfl_up(sc, d);
      if (t >= d) sc += u;
    }
    lh[t] = sc - v;
    lcur[t] = sc - v;
    if (t == 63) lh[64] = sc;
  }
  __syncthreads();
  for (int i = t; i < cnt; i += 256) {
    const u64 p = sb[i];
    const int rl = (int)((p >> 16) & (BROWS - 1));
    const int pos = atomicAdd(&lcur[rl], 1);
    ed[pos] = p;
  }
  __syncthreads();

  for (int j = lh[r0]; j < lh[r0 + 1]; ++j) {
    const u64 p = ed[j];
    const int col = (int)(p & 0xffffu);
    const float w = __uint_as_float((u32)(p >> 32));
    const uint4 q = reinterpret_cast<const uint4*>(he + ((size_t)col << 6))[l];
    a0[0] = fmaf(w, __uint_as_float(q.x << 16), a0[0]);
    a0[1] = fmaf(w, __uint_as_float(q.x & 0xffff0000u), a0[1]);
    a0[2] = fmaf(w, __uint_as_float(q.y << 16), a0[2]);
    a0[3] = fmaf(w, __uint_as_float(q.y & 0xffff0000u), a0[3]);
    a0[4] = fmaf(w, __uint_as_float(q.z << 16), a0[4]);
    a0[5] = fmaf(w, __uint_as_float(q.z & 0xffff0000u), a0[5]);
    a0[6] = fmaf(w, __uint_as_float(q.w << 16), a0[6]);
    a0[7] = fmaf(w, __uint_as_float(q.w & 0xffff0000u), a0[7]);
  }
  for (int j = lh[r1]; j < lh[r1 + 1]; ++j) {
    const u64 p = ed[j];
    const int col = (int)(p & 0xffffu);
    const float w = __uint_as_float((u32)(p >> 32));
    const uint4 q = reinterpret_cast<const uint4*>(he + ((size_t)col << 6))[l];
    a1[0] = fmaf(w, __uint_as_float(q.x << 16), a1[0]);
    a1[1] = fmaf(w, __uint_as_float(q.x & 0xffff0000u), a1[1]);
    a1[2] = fmaf(w, __uint_as_float(q.y << 16), a1[2]);
    a1[3] = fmaf(w, __uint_as_float(q.y & 0xffff0000u), a1[3]);
    a1[4] = fmaf(w, __uint_as_float(q.z << 16), a1[4]);
    a1[5] = fmaf(w, __uint_as_float(q.z & 0xffff0000u), a1[5]);
    a1[6] = fmaf(w, __uint_as_float(q.w << 16), a1[6]);
    a1[7] = fmaf(w, __uint_as_float(q.w & 0xffff0000u), a1[7]);
  }

  // spill-scan: normally nspill == 0 -> one scalar load + skip.
  const int ns = nspill[0];
  for (int sidx = 0; sidx < ns; ++sidx) {
    const u64 p = spill[sidx];
    const int grow = (int)((p >> 16) & 0xffffu);
    if ((grow >> BSH) != b) continue;
    const int rl = grow & (BROWS - 1);
    if (rl != r0 && rl != r1) continue;
    const int col = (int)(p & 0xffffu);
    const float w = __uint_as_float((u32)(p >> 32));
    const uint4 q = reinterpret_cast<const uint4*>(he + ((size_t)col << 6))[l];
    float* a = (rl == r0) ? a0 : a1;
    a[0] = fmaf(w, __uint_as_float(q.x << 16), a[0]);
    a[1] = fmaf(w, __uint_as_float(q.x & 0xffff0000u), a[1]);
    a[2] = fmaf(w, __uint_as_float(q.y << 16), a[2]);
    a[3] = fmaf(w, __uint_as_float(q.y & 0xffff0000u), a[3]);
    a[4] = fmaf(w, __uint_as_float(q.z << 16), a[4]);
    a[5] = fmaf(w, __uint_as_float(q.z & 0xffff0000u), a[5]);
    a[6] = fmaf(w, __uint_as_float(q.w << 16), a[6]);
    a[7] = fmaf(w, __uint_as_float(q.w & 0xffff0000u), a[7]);
  }

  // epilogue: out = proj(expmap0(relu(acc)))  (8-lane group reduce)
  const float maxn = 1.0f - 4e-3f;
  {
    float ss = 0.f;
    #pragma unroll
    for (int k = 0; k < 8; ++k) { a0[k] = fmaxf(a0[k], 0.f); ss = fmaf(a0[k], a0[k], ss); }
    ss += __shfl_xor(ss, 1); ss += __shfl_xor(ss, 2); ss += __shfl_xor(ss, 4);
    const float nu = fmaxf(sqrtf(ss), 1e-15f);
    const float th = tanhf(nu);
    const float scale = (th > maxn) ? (maxn / nu) : (th / nu);
    const int grow = (b << BSH) + r0;
    if (grow < n) {
      float4* op = reinterpret_cast<float4*>(out + (size_t)grow * DD + (size_t)l * 8);
      op[0] = float4{a0[0] * scale, a0[1] * scale, a0[2] * scale, a0[3] * scale};
      op[1] = float4{a0[4] * scale, a0[5] * scale, a0[6] * scale, a0[7] * scale};
    }
  }
  {
    float ss = 0.f;
    #pragma unroll
    for (int k = 0; k < 8; ++k) { a1[k] = fmaxf(a1[k], 0.f); ss = fmaf(a1[k], a1[k], ss); }
    ss += __shfl_xor(ss, 1); ss += __shfl_xor(ss, 2); ss += __shfl_xor(ss, 4);
    const float nu = fmaxf(sqrtf(ss), 1e-15f);
    const float th = tanhf(nu);
    const float scale = (th > maxn) ? (maxn / nu) : (th / nu);
    const int grow = (b << BSH) + r1;
    if (grow < n) {
      float4* op = reinterpret_cast<float4*>(out + (size_t)grow * DD + (size_t)l * 8);
      op[0] = float4{a1[0] * scale, a1[1] * scale, a1[2] * scale, a1[3] * scale};
      op[1] = float4{a1[4] * scale, a1[5] * scale, a1[6] * scale, a1[7] * scale};
    }
  }
}

// ---------------------------------------------------------------------------
// Deep fallback (tiny ws): atomic scatter path, fp32.
// ---------------------------------------------------------------------------
__global__ __launch_bounds__(256) void hgcn_linf32(const float* __restrict__ x,
                                                   const float* __restrict__ W,
                                                   float* __restrict__ he, int n) {
  __shared__ float Wl[64][68];
  __shared__ float xs[4][64];
  const int tid = threadIdx.x;
  for (int i = tid; i < 64 * 64; i += 256) Wl[i >> 6][i & 63] = W[i];
  const int wave = tid >> 6, lane = tid & 63;
  const int row = blockIdx.x * 4 + wave;
  float xv = 0.f;
  if (row < n) xv = x[row * DD + lane];
  xs[wave][lane] = xv;
  __syncthreads();
  if (row >= n) return;
  float nx2 = xv * xv;
  #pragma unroll
  for (int m = 1; m < 64; m <<= 1) nx2 += __shfl_xor(nx2, m);
  const float nx = fmaxf(sqrtf(nx2), 1e-15f);
  const float s = atanhf(fminf(nx, 1.f - 1e-7f)) / nx;
  const int j0 = (lane >> 3) & 7;
  float acc = 0.f;
  #pragma unroll
  for (int jj = 0; jj < 16; ++jj) {
    const int k = ((jj + j0) & 15) << 2;
    const float4 xk = *reinterpret_cast<const float4*>(&xs[wave][k]);
    const float4 wk = *reinterpret_cast<const float4*>(&Wl[lane][k]);
    acc = fmaf(xk.x, wk.x, acc); acc = fmaf(xk.y, wk.y, acc);
    acc = fmaf(xk.z, wk.z, acc); acc = fmaf(xk.w, wk.w, acc);
  }
  he[row * DD + lane] = acc * s;
}

__global__ __launch_bounds__(256) void hgcn_zero(float* __restrict__ p, int n4) {
  const int i = blockIdx.x * 256 + threadIdx.x;
  if (i < n4) reinterpret_cast<float4*>(p)[i] = float4{0.f, 0.f, 0.f, 0.f};
}

__global__ __launch_bounds__(256) void hgcn_scatter(const float* __restrict__ he,
                                                    const int* __restrict__ ei,
                                                    const float* __restrict__ ew,
                                                    float* __restrict__ sup, int ne) {
  const int t = blockIdx.x * 256 + threadIdx.x;
  const int e = t >> 4, l = t & 15;
  if (e >= ne) return;
  const int row = ei[e];
  const int col = ei[ne + e];
  const float w = ew[e];
  const float4 v = *reinterpret_cast<const float4*>(he + (size_t)col * DD + l * 4);
  float* dst = sup + (size_t)row * DD + l * 4;
  unsafeAtomicAdd(dst + 0, w * v.x);
  unsafeAtomicAdd(dst + 1, w * v.y);
  unsafeAtomicAdd(dst + 2, w * v.z);
  unsafeAtomicAdd(dst + 3, w * v.w);
}

__global__ __launch_bounds__(256) void hgcn_final(const float* __restrict__ sup,
                                                  float* __restrict__ out, int n) {
  const int t = blockIdx.x * 256 + threadIdx.x;
  const int r = t >> 4, l = t & 15;
  if (r >= n) return;
  float4 v = *reinterpret_cast<const float4*>(sup + (size_t)r * DD + l * 4);
  v.x = fmaxf(v.x, 0.f); v.y = fmaxf(v.y, 0.f);
  v.z = fmaxf(v.z, 0.f); v.w = fmaxf(v.w, 0.f);
  float p = v.x*v.x + v.y*v.y + v.z*v.z + v.w*v.w;
  p += __shfl_xor(p, 1); p += __shfl_xor(p, 2);
  p += __shfl_xor(p, 4); p += __shfl_xor(p, 8);
  const float nu = fmaxf(sqrtf(p), 1e-15f);
  const float th = tanhf(nu);
  float scale = th / nu;
  const float maxn = 1.0f - 4e-3f;
  if (th > maxn) scale = maxn / nu;
  float4 o = {v.x*scale, v.y*scale, v.z*scale, v.w*scale};
  *reinterpret_cast<float4*>(out + (size_t)r * DD + l * 4) = o;
}

extern "C" void kernel_launch(void* const* d_in, const int* in_sizes, int n_in,
                              void* d_out, int out_size, void* d_ws, size_t ws_size,
                              hipStream_t stream) {
  const float* x  = (const float*)d_in[0];
  const float* W  = (const float*)d_in[1];
  const float* ew = (const float*)d_in[2];
  const int*   ei = (const int*)d_in[3];
  const int n  = in_sizes[0] / DD;          // 50000
  const int ne = in_sizes[2];               // 800000
  const int nb = (n + BROWS - 1) / BROWS;   // buckets (782)

  // ws layout (16B-aligned blocks)
  size_t off_he    = 0;
  size_t off_stage = off_he + (((size_t)n * DD * 2 + 15) / 16) * 16;
  size_t off_spill = off_stage + (size_t)MAXB * CAPB * 8;
  size_t off_bcur  = off_spill + (size_t)ne * 8;
  size_t off_nsp   = off_bcur + MAXB * 4;
  size_t need      = off_nsp + 64;

  // performance guard only (overflow is correctness-safe via spill):
  // mean + 8*sqrt(mean) must fit in CAPB
  const size_t mean = (size_t)ne / (size_t)nb;
  size_t sig = 1;
  while (sig * sig < mean) ++sig;           // ceil(sqrt(mean)), tiny loop on host
  const bool capOK = mean + 8 * sig <= CAPB;

  if (ws_size >= need && n <= 65535 && nb <= MAXB && capOK) {
    __hip_bfloat16* he = (__hip_bfloat16*)((char*)d_ws + off_he);
    u64* stage  = (u64*)((char*)d_ws + off_stage);
    u64* spill  = (u64*)((char*)d_ws + off_spill);
    int* bcur   = (int*)((char*)d_ws + off_bcur);
    int* nspill = (int*)((char*)d_ws + off_nsp);
    float* out  = (float*)d_out;

    hipLaunchKernelGGL(hgcn_linear, dim3((n + 15) / 16),           dim3(256),  0, stream,
                       x, W, he, bcur, nspill, n);
    hipLaunchKernelGGL(hgcn_bin,    dim3((ne + BINC - 1) / BINC),  dim3(BINB), 0, stream,
                       ei, ew, bcur, stage, spill, nspill, ne);
    hipLaunchKernelGGL(hgcn_bagg,   dim3(nb),                      dim3(256),  0, stream,
                       (const u16*)he, stage, bcur, spill, nspill, out, n);
  } else {
    float* he  = (float*)d_out;
    float* sup = (float*)d_ws;
    float* out = (float*)d_out;
    const int n4 = n * DD / 4;
    hipLaunchKernelGGL(hgcn_zero,    dim3((n4 + 255) / 256),       dim3(256), 0, stream, sup, n4);
    hipLaunchKernelGGL(hgcn_linf32,  dim3((n + 3) / 4),            dim3(256), 0, stream, x, W, he, n);
    hipLaunchKernelGGL(hgcn_scatter, dim3((ne * 16 + 255) / 256),  dim3(256), 0, stream, he, ei, ew, sup, ne);
    hipLaunchKernelGGL(hgcn_final,   dim3((n * 16 + 255) / 256),   dim3(256), 0, stream, sup, out, n);
  }
}

// Round 8
// 71.321 us; speedup vs baseline: 10.2636x; 1.0941x over previous
//
#include <hip/hip_runtime.h>
#include <hip/hip_bf16.h>
#include <math.h>

#define DD 64
#define BROWS 64            // rows per bucket
#define BSH 6               // log2(BROWS)
#define MAXB 1024           // max buckets supported
#define CAPB 1536           // fixed bucket capacity (mean + >8 sigma headroom)
typedef unsigned long long u64;
typedef unsigned int u32;
typedef unsigned short u16;

// ---------------------------------------------------------------------------
// Linear: he = bf16( (x @ W^T) * artanh(||x||)/||x|| )  (exact telescoped
// logmap0(mobius_matvec(W,x,c=1))). 16 rows/block. Block 0 zeroes bucket
// cursors + spill counter (stream order puts it before hgcn_bin).
// ---------------------------------------------------------------------------
__global__ __launch_bounds__(256) void hgcn_linear(const float* __restrict__ x,
                                                   const float* __restrict__ W,
                                                   __hip_bfloat16* __restrict__ he,
                                                   int* __restrict__ bcur,
                                                   int* __restrict__ nspill,
                                                   int n) {
  if (blockIdx.x == 0) {
    for (int i = threadIdx.x; i < MAXB; i += 256) bcur[i] = 0;
    if (threadIdx.x == 0) nspill[0] = 0;
  }
  __shared__ float Wl[64][68];     // stride-68 + per-lane k-rotation: no 8-way conflicts
  __shared__ float xs[16][64];
  const int tid = threadIdx.x;
  for (int i = tid; i < 64 * 64; i += 256) Wl[i >> 6][i & 63] = W[i];
  const int wave = tid >> 6, lane = tid & 63;
  const int rbase = blockIdx.x * 16 + wave * 4;
  float xv[4];
  #pragma unroll
  for (int q = 0; q < 4; ++q) {
    const int row = rbase + q;
    xv[q] = (row < n) ? x[(size_t)row * DD + lane] : 0.f;
    xs[wave * 4 + q][lane] = xv[q];
  }
  __syncthreads();

  const int j0 = (lane >> 3) & 7;
  #pragma unroll
  for (int q = 0; q < 4; ++q) {
    const int row = rbase + q;
    if (row >= n) break;
    float nx2 = xv[q] * xv[q];
    #pragma unroll
    for (int m = 1; m < 64; m <<= 1) nx2 += __shfl_xor(nx2, m);
    const float nx = fmaxf(sqrtf(nx2), 1e-15f);
    const float s  = atanhf(fminf(nx, 1.f - 1e-7f)) / nx;
    float acc = 0.f;
    #pragma unroll
    for (int jj = 0; jj < 16; ++jj) {
      const int k = ((jj + j0) & 15) << 2;
      const float4 xk = *reinterpret_cast<const float4*>(&xs[wave * 4 + q][k]);
      const float4 wk = *reinterpret_cast<const float4*>(&Wl[lane][k]);
      acc = fmaf(xk.x, wk.x, acc);
      acc = fmaf(xk.y, wk.y, acc);
      acc = fmaf(xk.z, wk.z, acc);
      acc = fmaf(xk.w, wk.w, acc);
    }
    he[(size_t)row * DD + lane] = __float2bfloat16(acc * s);
  }
}

// ---------------------------------------------------------------------------
// Bin (single pass over edges): per-block LDS hist -> one contiguous run
// reservation per bucket (fixed base b*CAPB) -> near-coalesced writes.
// Edges beyond CAPB go to the spill list (cap = ne, fully safe; ~never hit).
// Packed edge: w:f32<<32 | rowLocal:6<<16 | col:16.  Spill: w<<32|rowGlobal:16<<16|col.
// ---------------------------------------------------------------------------
#define BINB 1024
#define BINC 6144
__global__ __launch_bounds__(1024) void hgcn_bin(const int* __restrict__ ei,
                                                 const float* __restrict__ ew,
                                                 int* __restrict__ bcur,
                                                 u64* __restrict__ stage,
                                                 u64* __restrict__ spill,
                                                 int* __restrict__ nspill,
                                                 int ne) {
  __shared__ int h[MAXB], cur[MAXB], gp[MAXB];
  const int tid = threadIdx.x;
  h[tid] = 0; cur[tid] = 0;
  __syncthreads();
  const int eb = blockIdx.x * BINC;
  const int m = min(BINC, ne - eb);
  for (int i = tid; i < m; i += BINB) atomicAdd(&h[ei[eb + i] >> BSH], 1);
  __syncthreads();
  gp[tid] = h[tid] ? atomicAdd(&bcur[tid], h[tid]) : 0;
  __syncthreads();
  for (int i = tid; i < m; i += BINB) {
    const int r = ei[eb + i];
    const int c = ei[ne + eb + i];
    const float w = ew[eb + i];
    const int b = r >> BSH;
    const int pos = gp[b] + atomicAdd(&cur[b], 1);
    if (pos < CAPB) {
      stage[(size_t)b * CAPB + pos] =
          ((u64)__float_as_uint(w) << 32) | ((u32)(r & (BROWS - 1)) << 16) | (u32)c;
    } else {
      const int sp = atomicAdd(nspill, 1);
      spill[sp] = ((u64)__float_as_uint(w) << 32) | ((u32)(r & 0xffff) << 16) | (u32)c;
    }
  }
}

// ---------------------------------------------------------------------------
// Bucket aggregate + fused epilogue (NO fp atomics).
//  - LDS counting sort by local row (int ds_add cursors + ds_write_b64)
//  - 1024 threads = 64 rows x 16 lanes; per row: 2 edge-slots x 8 lanes,
//    stride-2 edge walk with 1-deep prefetch -> 2 independent gather chains
//    per row, ~4x shorter serial depth than the 2-rows-per-8-lane-group form.
//  - slot partials merged with one shfl_xor(8); spill-scan (normally empty);
//    out = proj(expmap0(relu(acc))), direct coalesced store.
// ---------------------------------------------------------------------------
__global__ __launch_bounds__(1024) void hgcn_bagg(const u16* __restrict__ he,
                                                  const u64* __restrict__ stage,
                                                  const int* __restrict__ bcur,
                                                  const u64* __restrict__ spill,
                                                  const int* __restrict__ nspill,
                                                  float* __restrict__ out, int n) {
  __shared__ u64 ed[CAPB];
  __shared__ int lh[BROWS + 1];
  __shared__ int lcur[BROWS];
  const int t = threadIdx.x;
  const int b = blockIdx.x;
  const u64* sb = stage + (size_t)b * CAPB;
  const int cnt = min(bcur[b], CAPB);

  if (t < BROWS) lcur[t] = 0;
  __syncthreads();
  for (int i = t; i < cnt; i += 1024)
    atomicAdd(&lcur[(int)((sb[i] >> 16) & (BROWS - 1))], 1);
  __syncthreads();
  if (t < 64) {
    const int v = lcur[t];
    int sc = v;
    #pragma unroll
    for (int d = 1; d < 64; d <<= 1) {
      const int u2 = __shfl_up(sc, d);
      if (t >= d) sc += u2;
    }
    lh[t] = sc - v;
    lcur[t] = sc - v;
    if (t == 63) lh[64] = sc;
  }
  __syncthreads();
  for (int i = t; i < cnt; i += 1024) {
    const u64 p = sb[i];
    const int rl = (int)((p >> 16) & (BROWS - 1));
    const int pos = atomicAdd(&lcur[rl], 1);
    ed[pos] = p;
  }
  __syncthreads();

  const int row = t >> 4;          // 0..63
  const int u = t & 15;
  const int s = u >> 3;            // slot 0/1
  const int l = u & 7;             // 8 lanes split D=64 as 8x8
  float a[8] = {0.f, 0.f, 0.f, 0.f, 0.f, 0.f, 0.f, 0.f};

  int j = lh[row] + s;
  const int je = lh[row + 1];
  uint4 q = {0, 0, 0, 0};
  float w = 0.f;
  if (j < je) {
    const u64 p = ed[j];
    w = __uint_as_float((u32)(p >> 32));
    q = reinterpret_cast<const uint4*>(he + ((size_t)(p & 0xffffu) << 6))[l];
  }
  while (j < je) {
    const uint4 qc = q;
    const float wc = w;
    const int jn = j + 2;
    if (jn < je) {
      const u64 p = ed[jn];
      w = __uint_as_float((u32)(p >> 32));
      q = reinterpret_cast<const uint4*>(he + ((size_t)(p & 0xffffu) << 6))[l];
    }
    a[0] = fmaf(wc, __uint_as_float(qc.x << 16), a[0]);
    a[1] = fmaf(wc, __uint_as_float(qc.x & 0xffff0000u), a[1]);
    a[2] = fmaf(wc, __uint_as_float(qc.y << 16), a[2]);
    a[3] = fmaf(wc, __uint_as_float(qc.y & 0xffff0000u), a[3]);
    a[4] = fmaf(wc, __uint_as_float(qc.z << 16), a[4]);
    a[5] = fmaf(wc, __uint_as_float(qc.z & 0xffff0000u), a[5]);
    a[6] = fmaf(wc, __uint_as_float(qc.w << 16), a[6]);
    a[7] = fmaf(wc, __uint_as_float(qc.w & 0xffff0000u), a[7]);
    j = jn;
  }

  // spill-scan: normally nspill == 0 -> one scalar load + skip. Slot 0 only.
  const int ns = nspill[0];
  for (int sidx = 0; sidx < ns; ++sidx) {
    const u64 p = spill[sidx];
    const int grow = (int)((p >> 16) & 0xffffu);
    if ((grow >> BSH) != b) continue;
    if ((grow & (BROWS - 1)) != row || s != 0) continue;
    const float ww = __uint_as_float((u32)(p >> 32));
    const uint4 qq = reinterpret_cast<const uint4*>(he + ((size_t)(p & 0xffffu) << 6))[l];
    a[0] = fmaf(ww, __uint_as_float(qq.x << 16), a[0]);
    a[1] = fmaf(ww, __uint_as_float(qq.x & 0xffff0000u), a[1]);
    a[2] = fmaf(ww, __uint_as_float(qq.y << 16), a[2]);
    a[3] = fmaf(ww, __uint_as_float(qq.y & 0xffff0000u), a[3]);
    a[4] = fmaf(ww, __uint_as_float(qq.z << 16), a[4]);
    a[5] = fmaf(ww, __uint_as_float(qq.z & 0xffff0000u), a[5]);
    a[6] = fmaf(ww, __uint_as_float(qq.w << 16), a[6]);
    a[7] = fmaf(ww, __uint_as_float(qq.w & 0xffff0000u), a[7]);
  }

  // merge the two slots (lane u and u^8 hold the two partials)
  #pragma unroll
  for (int k = 0; k < 8; ++k) a[k] += __shfl_xor(a[k], 8);

  // epilogue: out = proj(expmap0(relu(acc)))  (8-lane reduce for the norm)
  float ss = 0.f;
  #pragma unroll
  for (int k = 0; k < 8; ++k) { a[k] = fmaxf(a[k], 0.f); ss = fmaf(a[k], a[k], ss); }
  ss += __shfl_xor(ss, 1); ss += __shfl_xor(ss, 2); ss += __shfl_xor(ss, 4);
  const float nu = fmaxf(sqrtf(ss), 1e-15f);
  const float th = tanhf(nu);
  const float maxn = 1.0f - 4e-3f;
  const float scale = (th > maxn) ? (maxn / nu) : (th / nu);
  const int grow = (b << BSH) + row;
  if (s == 0 && grow < n) {
    float4* op = reinterpret_cast<float4*>(out + (size_t)grow * DD + (size_t)l * 8);
    op[0] = float4{a[0] * scale, a[1] * scale, a[2] * scale, a[3] * scale};
    op[1] = float4{a[4] * scale, a[5] * scale, a[6] * scale, a[7] * scale};
  }
}

// ---------------------------------------------------------------------------
// Deep fallback (tiny ws): atomic scatter path, fp32.
// ---------------------------------------------------------------------------
__global__ __launch_bounds__(256) void hgcn_linf32(const float* __restrict__ x,
                                                   const float* __restrict__ W,
                                                   float* __restrict__ he, int n) {
  __shared__ float Wl[64][68];
  __shared__ float xs[4][64];
  const int tid = threadIdx.x;
  for (int i = tid; i < 64 * 64; i += 256) Wl[i >> 6][i & 63] = W[i];
  const int wave = tid >> 6, lane = tid & 63;
  const int row = blockIdx.x * 4 + wave;
  float xv = 0.f;
  if (row < n) xv = x[row * DD + lane];
  xs[wave][lane] = xv;
  __syncthreads();
  if (row >= n) return;
  float nx2 = xv * xv;
  #pragma unroll
  for (int m = 1; m < 64; m <<= 1) nx2 += __shfl_xor(nx2, m);
  const float nx = fmaxf(sqrtf(nx2), 1e-15f);
  const float s = atanhf(fminf(nx, 1.f - 1e-7f)) / nx;
  const int j0 = (lane >> 3) & 7;
  float acc = 0.f;
  #pragma unroll
  for (int jj = 0; jj < 16; ++jj) {
    const int k = ((jj + j0) & 15) << 2;
    const float4 xk = *reinterpret_cast<const float4*>(&xs[wave][k]);
    const float4 wk = *reinterpret_cast<const float4*>(&Wl[lane][k]);
    acc = fmaf(xk.x, wk.x, acc); acc = fmaf(xk.y, wk.y, acc);
    acc = fmaf(xk.z, wk.z, acc); acc = fmaf(xk.w, wk.w, acc);
  }
  he[row * DD + lane] = acc * s;
}

__global__ __launch_bounds__(256) void hgcn_zero(float* __restrict__ p, int n4) {
  const int i = blockIdx.x * 256 + threadIdx.x;
  if (i < n4) reinterpret_cast<float4*>(p)[i] = float4{0.f, 0.f, 0.f, 0.f};
}

__global__ __launch_bounds__(256) void hgcn_scatter(const float* __restrict__ he,
                                                    const int* __restrict__ ei,
                                                    const float* __restrict__ ew,
                                                    float* __restrict__ sup, int ne) {
  const int t = blockIdx.x * 256 + threadIdx.x;
  const int e = t >> 4, l = t & 15;
  if (e >= ne) return;
  const int row = ei[e];
  const int col = ei[ne + e];
  const float w = ew[e];
  const float4 v = *reinterpret_cast<const float4*>(he + (size_t)col * DD + l * 4);
  float* dst = sup + (size_t)row * DD + l * 4;
  unsafeAtomicAdd(dst + 0, w * v.x);
  unsafeAtomicAdd(dst + 1, w * v.y);
  unsafeAtomicAdd(dst + 2, w * v.z);
  unsafeAtomicAdd(dst + 3, w * v.w);
}

__global__ __launch_bounds__(256) void hgcn_final(const float* __restrict__ sup,
                                                  float* __restrict__ out, int n) {
  const int t = blockIdx.x * 256 + threadIdx.x;
  const int r = t >> 4, l = t & 15;
  if (r >= n) return;
  float4 v = *reinterpret_cast<const float4*>(sup + (size_t)r * DD + l * 4);
  v.x = fmaxf(v.x, 0.f); v.y = fmaxf(v.y, 0.f);
  v.z = fmaxf(v.z, 0.f); v.w = fmaxf(v.w, 0.f);
  float p = v.x*v.x + v.y*v.y + v.z*v.z + v.w*v.w;
  p += __shfl_xor(p, 1); p += __shfl_xor(p, 2);
  p += __shfl_xor(p, 4); p += __shfl_xor(p, 8);
  const float nu = fmaxf(sqrtf(p), 1e-15f);
  const float th = tanhf(nu);
  float scale = th / nu;
  const float maxn = 1.0f - 4e-3f;
  if (th > maxn) scale = maxn / nu;
  float4 o = {v.x*scale, v.y*scale, v.z*scale, v.w*scale};
  *reinterpret_cast<float4*>(out + (size_t)r * DD + l * 4) = o;
}

extern "C" void kernel_launch(void* const* d_in, const int* in_sizes, int n_in,
                              void* d_out, int out_size, void* d_ws, size_t ws_size,
                              hipStream_t stream) {
  const float* x  = (const float*)d_in[0];
  const float* W  = (const float*)d_in[1];
  const float* ew = (const float*)d_in[2];
  const int*   ei = (const int*)d_in[3];
  const int n  = in_sizes[0] / DD;          // 50000
  const int ne = in_sizes[2];               // 800000
  const int nb = (n + BROWS - 1) / BROWS;   // buckets (782)

  // ws layout (16B-aligned blocks)
  size_t off_he    = 0;
  size_t off_stage = off_he + (((size_t)n * DD * 2 + 15) / 16) * 16;
  size_t off_spill = off_stage + (size_t)MAXB * CAPB * 8;
  size_t off_bcur  = off_spill + (size_t)ne * 8;
  size_t off_nsp   = off_bcur + MAXB * 4;
  size_t need      = off_nsp + 64;

  // performance guard only (overflow is correctness-safe via spill):
  // mean + 8*sqrt(mean) must fit in CAPB
  const size_t mean = (size_t)ne / (size_t)nb;
  size_t sig = 1;
  while (sig * sig < mean) ++sig;           // ceil(sqrt(mean))
  const bool capOK = mean + 8 * sig <= CAPB;

  if (ws_size >= need && n <= 65535 && nb <= MAXB && capOK) {
    __hip_bfloat16* he = (__hip_bfloat16*)((char*)d_ws + off_he);
    u64* stage  = (u64*)((char*)d_ws + off_stage);
    u64* spill  = (u64*)((char*)d_ws + off_spill);
    int* bcur   = (int*)((char*)d_ws + off_bcur);
    int* nspill = (int*)((char*)d_ws + off_nsp);
    float* out  = (float*)d_out;

    hipLaunchKernelGGL(hgcn_linear, dim3((n + 15) / 16),           dim3(256),  0, stream,
                       x, W, he, bcur, nspill, n);
    hipLaunchKernelGGL(hgcn_bin,    dim3((ne + BINC - 1) / BINC),  dim3(BINB), 0, stream,
                       ei, ew, bcur, stage, spill, nspill, ne);
    hipLaunchKernelGGL(hgcn_bagg,   dim3(nb),                      dim3(1024), 0, stream,
                       (const u16*)he, stage, bcur, spill, nspill, out, n);
  } else {
    float* he  = (float*)d_out;
    float* sup = (float*)d_ws;
    float* out = (float*)d_out;
    const int n4 = n * DD / 4;
    hipLaunchKernelGGL(hgcn_zero,    dim3((n4 + 255) / 256),       dim3(256), 0, stream, sup, n4);
    hipLaunchKernelGGL(hgcn_linf32,  dim3((n + 3) / 4),            dim3(256), 0, stream, x, W, he, n);
    hipLaunchKernelGGL(hgcn_scatter, dim3((ne * 16 + 255) / 256),  dim3(256), 0, stream, he, ei, ew, sup, ne);
    hipLaunchKernelGGL(hgcn_final,   dim3((n * 16 + 255) / 256),   dim3(256), 0, stream, sup, out, n);
  }
}

// Round 9
// 68.070 us; speedup vs baseline: 10.7538x; 1.0478x over previous
//
#include <hip/hip_runtime.h>
#include <hip/hip_bf16.h>
#include <math.h>

#define DD 64
#define BROWS 64            // rows per bucket
#define BSH 6               // log2(BROWS)
#define MAXB 1024           // max buckets supported
#define CAPB 1536           // fixed bucket capacity (mean + >8 sigma headroom)
#define BINB 1024
#define BINC 6144
typedef unsigned long long u64;
typedef unsigned int u32;
typedef unsigned short u16;

// ---------------------------------------------------------------------------
// K0: zero bucket cursors + spill counter (1 block; stream order precedes linbin).
// (Not hipMemsetAsync: runtime fill kernels measured pathologically slow, R3.)
// ---------------------------------------------------------------------------
__global__ __launch_bounds__(1024) void hgcn_zero0(int* __restrict__ bcur,
                                                   int* __restrict__ nspill) {
  const int i = threadIdx.x;
  if (i < MAXB) bcur[i] = 0;
  if (i == 0) nspill[0] = 0;
}

// ---------------------------------------------------------------------------
// Fused linear+bin. The two phases have disjoint inputs, so their blocks
// co-schedule: blockIdx < nbin -> bin body; else -> linear body.
//
// bin: per-block LDS hist -> contiguous run reservation per bucket (fixed
// base b*CAPB) -> near-coalesced writes; overflow -> spill list (safe, ~never).
// Packed edge: w:f32<<32 | rowLocal:6<<16 | col:16.
//
// linear: he = bf16((x @ W^T) * artanh(||x||)/||x||)  (exact telescoped
// logmap0(mobius_matvec(W,x,c=1))); 64 rows/block, 16 waves x 4 rows.
// ---------------------------------------------------------------------------
__global__ __launch_bounds__(1024) void hgcn_linbin(const float* __restrict__ x,
                                                    const float* __restrict__ W,
                                                    __hip_bfloat16* __restrict__ he,
                                                    const int* __restrict__ ei,
                                                    const float* __restrict__ ew,
                                                    int* __restrict__ bcur,
                                                    u64* __restrict__ stage,
                                                    u64* __restrict__ spill,
                                                    int* __restrict__ nspill,
                                                    int n, int ne, int nbin) {
  const int tid = threadIdx.x;
  if ((int)blockIdx.x < nbin) {
    // ------------------------------ bin ------------------------------------
    __shared__ int h[MAXB], cur[MAXB], gp[MAXB];
    h[tid] = 0; cur[tid] = 0;
    __syncthreads();
    const int eb = blockIdx.x * BINC;
    const int m = min(BINC, ne - eb);
    for (int i = tid; i < m; i += BINB) atomicAdd(&h[ei[eb + i] >> BSH], 1);
    __syncthreads();
    gp[tid] = h[tid] ? atomicAdd(&bcur[tid], h[tid]) : 0;
    __syncthreads();
    for (int i = tid; i < m; i += BINB) {
      const int r = ei[eb + i];
      const int c = ei[ne + eb + i];
      const float w = ew[eb + i];
      const int b = r >> BSH;
      const int pos = gp[b] + atomicAdd(&cur[b], 1);
      if (pos < CAPB) {
        stage[(size_t)b * CAPB + pos] =
            ((u64)__float_as_uint(w) << 32) | ((u32)(r & (BROWS - 1)) << 16) | (u32)c;
      } else {
        const int sp = atomicAdd(nspill, 1);
        spill[sp] = ((u64)__float_as_uint(w) << 32) | ((u32)(r & 0xffff) << 16) | (u32)c;
      }
    }
  } else {
    // ----------------------------- linear ----------------------------------
    __shared__ float Wl[64][68];   // stride-68 + per-lane k-rotation: conflict-free
    __shared__ float xs[64][64];
    const int lb = blockIdx.x - nbin;
    for (int i = tid; i < 64 * 64; i += 1024) Wl[i >> 6][i & 63] = W[i];
    const int wave = tid >> 6, lane = tid & 63;
    const int rbase = lb * 64 + wave * 4;
    float xv[4];
    #pragma unroll
    for (int q = 0; q < 4; ++q) {
      const int row = rbase + q;
      xv[q] = (row < n) ? x[(size_t)row * DD + lane] : 0.f;
      xs[wave * 4 + q][lane] = xv[q];
    }
    __syncthreads();
    const int j0 = (lane >> 3) & 7;
    #pragma unroll
    for (int q = 0; q < 4; ++q) {
      const int row = rbase + q;
      if (row >= n) break;
      float nx2 = xv[q] * xv[q];
      #pragma unroll
      for (int m = 1; m < 64; m <<= 1) nx2 += __shfl_xor(nx2, m);
      const float nx = fmaxf(sqrtf(nx2), 1e-15f);
      const float s  = atanhf(fminf(nx, 1.f - 1e-7f)) / nx;
      float acc = 0.f;
      #pragma unroll
      for (int jj = 0; jj < 16; ++jj) {
        const int k = ((jj + j0) & 15) << 2;
        const float4 xk = *reinterpret_cast<const float4*>(&xs[wave * 4 + q][k]);
        const float4 wk = *reinterpret_cast<const float4*>(&Wl[lane][k]);
        acc = fmaf(xk.x, wk.x, acc);
        acc = fmaf(xk.y, wk.y, acc);
        acc = fmaf(xk.z, wk.z, acc);
        acc = fmaf(xk.w, wk.w, acc);
      }
      he[(size_t)row * DD + lane] = __float2bfloat16(acc * s);
    }
  }
}

// ---------------------------------------------------------------------------
// Bucket aggregate + fused epilogue (NO fp atomics).
//  - stage chunk copied to LDS once (coalesced); hist/scan/permute all in LDS
//  - 64 rows x 16 lanes; 2 edge-slots x 8 lanes per row, stride-2 walk with
//    1-deep prefetch (2 independent gather chains per row)
//  - slot merge via shfl_xor(8); spill-scan (normally empty);
//    out = proj(expmap0(relu(acc))), direct coalesced store.
// ---------------------------------------------------------------------------
__global__ __launch_bounds__(1024) void hgcn_bagg(const u16* __restrict__ he,
                                                  const u64* __restrict__ stage,
                                                  const int* __restrict__ bcur,
                                                  const u64* __restrict__ spill,
                                                  const int* __restrict__ nspill,
                                                  float* __restrict__ out, int n) {
  __shared__ u64 edr[CAPB];
  __shared__ u64 ed[CAPB];
  __shared__ int lh[BROWS + 1];
  __shared__ int lcur[BROWS];
  const int t = threadIdx.x;
  const int b = blockIdx.x;
  const u64* sb = stage + (size_t)b * CAPB;
  const int cnt = min(bcur[b], CAPB);

  for (int i = t; i < cnt; i += 1024) edr[i] = sb[i];   // single global read
  if (t < BROWS) lcur[t] = 0;
  __syncthreads();
  for (int i = t; i < cnt; i += 1024)
    atomicAdd(&lcur[(int)((edr[i] >> 16) & (BROWS - 1))], 1);
  __syncthreads();
  if (t < 64) {
    const int v = lcur[t];
    int sc = v;
    #pragma unroll
    for (int d = 1; d < 64; d <<= 1) {
      const int u2 = __shfl_up(sc, d);
      if (t >= d) sc += u2;
    }
    lh[t] = sc - v;
    lcur[t] = sc - v;
    if (t == 63) lh[64] = sc;
  }
  __syncthreads();
  for (int i = t; i < cnt; i += 1024) {
    const u64 p = edr[i];
    const int rl = (int)((p >> 16) & (BROWS - 1));
    const int pos = atomicAdd(&lcur[rl], 1);
    ed[pos] = p;
  }
  __syncthreads();

  const int row = t >> 4;          // 0..63
  const int u = t & 15;
  const int s = u >> 3;            // slot 0/1
  const int l = u & 7;             // 8 lanes split D=64 as 8x8
  float a[8] = {0.f, 0.f, 0.f, 0.f, 0.f, 0.f, 0.f, 0.f};

  int j = lh[row] + s;
  const int je = lh[row + 1];
  uint4 q = {0, 0, 0, 0};
  float w = 0.f;
  if (j < je) {
    const u64 p = ed[j];
    w = __uint_as_float((u32)(p >> 32));
    q = reinterpret_cast<const uint4*>(he + ((size_t)(p & 0xffffu) << 6))[l];
  }
  while (j < je) {
    const uint4 qc = q;
    const float wc = w;
    const int jn = j + 2;
    if (jn < je) {
      const u64 p = ed[jn];
      w = __uint_as_float((u32)(p >> 32));
      q = reinterpret_cast<const uint4*>(he + ((size_t)(p & 0xffffu) << 6))[l];
    }
    a[0] = fmaf(wc, __uint_as_float(qc.x << 16), a[0]);
    a[1] = fmaf(wc, __uint_as_float(qc.x & 0xffff0000u), a[1]);
    a[2] = fmaf(wc, __uint_as_float(qc.y << 16), a[2]);
    a[3] = fmaf(wc, __uint_as_float(qc.y & 0xffff0000u), a[3]);
    a[4] = fmaf(wc, __uint_as_float(qc.z << 16), a[4]);
    a[5] = fmaf(wc, __uint_as_float(qc.z & 0xffff0000u), a[5]);
    a[6] = fmaf(wc, __uint_as_float(qc.w << 16), a[6]);
    a[7] = fmaf(wc, __uint_as_float(qc.w & 0xffff0000u), a[7]);
    j = jn;
  }

  // spill-scan: normally nspill == 0 -> one scalar load + skip. Slot 0 only.
  const int ns = nspill[0];
  for (int sidx = 0; sidx < ns; ++sidx) {
    const u64 p = spill[sidx];
    const int grow = (int)((p >> 16) & 0xffffu);
    if ((grow >> BSH) != b) continue;
    if ((grow & (BROWS - 1)) != row || s != 0) continue;
    const float ww = __uint_as_float((u32)(p >> 32));
    const uint4 qq = reinterpret_cast<const uint4*>(he + ((size_t)(p & 0xffffu) << 6))[l];
    a[0] = fmaf(ww, __uint_as_float(qq.x << 16), a[0]);
    a[1] = fmaf(ww, __uint_as_float(qq.x & 0xffff0000u), a[1]);
    a[2] = fmaf(ww, __uint_as_float(qq.y << 16), a[2]);
    a[3] = fmaf(ww, __uint_as_float(qq.y & 0xffff0000u), a[3]);
    a[4] = fmaf(ww, __uint_as_float(qq.z << 16), a[4]);
    a[5] = fmaf(ww, __uint_as_float(qq.z & 0xffff0000u), a[5]);
    a[6] = fmaf(ww, __uint_as_float(qq.w << 16), a[6]);
    a[7] = fmaf(ww, __uint_as_float(qq.w & 0xffff0000u), a[7]);
  }

  // merge the two slots (lanes u and u^8 hold the partials)
  #pragma unroll
  for (int k = 0; k < 8; ++k) a[k] += __shfl_xor(a[k], 8);

  // epilogue: out = proj(expmap0(relu(acc)))  (8-lane reduce for the norm)
  float ss = 0.f;
  #pragma unroll
  for (int k = 0; k < 8; ++k) { a[k] = fmaxf(a[k], 0.f); ss = fmaf(a[k], a[k], ss); }
  ss += __shfl_xor(ss, 1); ss += __shfl_xor(ss, 2); ss += __shfl_xor(ss, 4);
  const float nu = fmaxf(sqrtf(ss), 1e-15f);
  const float th = tanhf(nu);
  const float maxn = 1.0f - 4e-3f;
  const float scale = (th > maxn) ? (maxn / nu) : (th / nu);
  const int grow = (b << BSH) + row;
  if (s == 0 && grow < n) {
    float4* op = reinterpret_cast<float4*>(out + (size_t)grow * DD + (size_t)l * 8);
    op[0] = float4{a[0] * scale, a[1] * scale, a[2] * scale, a[3] * scale};
    op[1] = float4{a[4] * scale, a[5] * scale, a[6] * scale, a[7] * scale};
  }
}

// ---------------------------------------------------------------------------
// Deep fallback (tiny ws): atomic scatter path, fp32.
// ---------------------------------------------------------------------------
__global__ __launch_bounds__(256) void hgcn_linf32(const float* __restrict__ x,
                                                   const float* __restrict__ W,
                                                   float* __restrict__ he, int n) {
  __shared__ float Wl[64][68];
  __shared__ float xs[4][64];
  const int tid = threadIdx.x;
  for (int i = tid; i < 64 * 64; i += 256) Wl[i >> 6][i & 63] = W[i];
  const int wave = tid >> 6, lane = tid & 63;
  const int row = blockIdx.x * 4 + wave;
  float xv = 0.f;
  if (row < n) xv = x[row * DD + lane];
  xs[wave][lane] = xv;
  __syncthreads();
  if (row >= n) return;
  float nx2 = xv * xv;
  #pragma unroll
  for (int m = 1; m < 64; m <<= 1) nx2 += __shfl_xor(nx2, m);
  const float nx = fmaxf(sqrtf(nx2), 1e-15f);
  const float s = atanhf(fminf(nx, 1.f - 1e-7f)) / nx;
  const int j0 = (lane >> 3) & 7;
  float acc = 0.f;
  #pragma unroll
  for (int jj = 0; jj < 16; ++jj) {
    const int k = ((jj + j0) & 15) << 2;
    const float4 xk = *reinterpret_cast<const float4*>(&xs[wave][k]);
    const float4 wk = *reinterpret_cast<const float4*>(&Wl[lane][k]);
    acc = fmaf(xk.x, wk.x, acc); acc = fmaf(xk.y, wk.y, acc);
    acc = fmaf(xk.z, wk.z, acc); acc = fmaf(xk.w, wk.w, acc);
  }
  he[row * DD + lane] = acc * s;
}

__global__ __launch_bounds__(256) void hgcn_zero(float* __restrict__ p, int n4) {
  const int i = blockIdx.x * 256 + threadIdx.x;
  if (i < n4) reinterpret_cast<float4*>(p)[i] = float4{0.f, 0.f, 0.f, 0.f};
}

__global__ __launch_bounds__(256) void hgcn_scatter(const float* __restrict__ he,
                                                    const int* __restrict__ ei,
                                                    const float* __restrict__ ew,
                                                    float* __restrict__ sup, int ne) {
  const int t = blockIdx.x * 256 + threadIdx.x;
  const int e = t >> 4, l = t & 15;
  if (e >= ne) return;
  const int row = ei[e];
  const int col = ei[ne + e];
  const float w = ew[e];
  const float4 v = *reinterpret_cast<const float4*>(he + (size_t)col * DD + l * 4);
  float* dst = sup + (size_t)row * DD + l * 4;
  unsafeAtomicAdd(dst + 0, w * v.x);
  unsafeAtomicAdd(dst + 1, w * v.y);
  unsafeAtomicAdd(dst + 2, w * v.z);
  unsafeAtomicAdd(dst + 3, w * v.w);
}

__global__ __launch_bounds__(256) void hgcn_final(const float* __restrict__ sup,
                                                  float* __restrict__ out, int n) {
  const int t = blockIdx.x * 256 + threadIdx.x;
  const int r = t >> 4, l = t & 15;
  if (r >= n) return;
  float4 v = *reinterpret_cast<const float4*>(sup + (size_t)r * DD + l * 4);
  v.x = fmaxf(v.x, 0.f); v.y = fmaxf(v.y, 0.f);
  v.z = fmaxf(v.z, 0.f); v.w = fmaxf(v.w, 0.f);
  float p = v.x*v.x + v.y*v.y + v.z*v.z + v.w*v.w;
  p += __shfl_xor(p, 1); p += __shfl_xor(p, 2);
  p += __shfl_xor(p, 4); p += __shfl_xor(p, 8);
  const float nu = fmaxf(sqrtf(p), 1e-15f);
  const float th = tanhf(nu);
  float scale = th / nu;
  const float maxn = 1.0f - 4e-3f;
  if (th > maxn) scale = maxn / nu;
  float4 o = {v.x*scale, v.y*scale, v.z*scale, v.w*scale};
  *reinterpret_cast<float4*>(out + (size_t)r * DD + l * 4) = o;
}

extern "C" void kernel_launch(void* const* d_in, const int* in_sizes, int n_in,
                              void* d_out, int out_size, void* d_ws, size_t ws_size,
                              hipStream_t stream) {
  const float* x  = (const float*)d_in[0];
  const float* W  = (const float*)d_in[1];
  const float* ew = (const float*)d_in[2];
  const int*   ei = (const int*)d_in[3];
  const int n  = in_sizes[0] / DD;          // 50000
  const int ne = in_sizes[2];               // 800000
  const int nb = (n + BROWS - 1) / BROWS;   // buckets (782)

  // ws layout (16B-aligned blocks)
  size_t off_he    = 0;
  size_t off_stage = off_he + (((size_t)n * DD * 2 + 15) / 16) * 16;
  size_t off_spill = off_stage + (size_t)MAXB * CAPB * 8;
  size_t off_bcur  = off_spill + (size_t)ne * 8;
  size_t off_nsp   = off_bcur + MAXB * 4;
  size_t need      = off_nsp + 64;

  // performance guard only (overflow is correctness-safe via spill):
  // mean + 8*sqrt(mean) must fit in CAPB
  const size_t mean = (size_t)ne / (size_t)nb;
  size_t sig = 1;
  while (sig * sig < mean) ++sig;           // ceil(sqrt(mean))
  const bool capOK = mean + 8 * sig <= CAPB;

  if (ws_size >= need && n <= 65535 && nb <= MAXB && capOK) {
    __hip_bfloat16* he = (__hip_bfloat16*)((char*)d_ws + off_he);
    u64* stage  = (u64*)((char*)d_ws + off_stage);
    u64* spill  = (u64*)((char*)d_ws + off_spill);
    int* bcur   = (int*)((char*)d_ws + off_bcur);
    int* nspill = (int*)((char*)d_ws + off_nsp);
    float* out  = (float*)d_out;

    const int nbin = (ne + BINC - 1) / BINC;        // 131
    const int nlin = (n + 63) / 64;                 // 782

    hipLaunchKernelGGL(hgcn_zero0,  dim3(1),           dim3(1024), 0, stream, bcur, nspill);
    hipLaunchKernelGGL(hgcn_linbin, dim3(nbin + nlin), dim3(1024), 0, stream,
                       x, W, he, ei, ew, bcur, stage, spill, nspill, n, ne, nbin);
    hipLaunchKernelGGL(hgcn_bagg,   dim3(nb),          dim3(1024), 0, stream,
                       (const u16*)he, stage, bcur, spill, nspill, out, n);
  } else {
    float* he  = (float*)d_out;
    float* sup = (float*)d_ws;
    float* out = (float*)d_out;
    const int n4 = n * DD / 4;
    hipLaunchKernelGGL(hgcn_zero,    dim3((n4 + 255) / 256),       dim3(256), 0, stream, sup, n4);
    hipLaunchKernelGGL(hgcn_linf32,  dim3((n + 3) / 4),            dim3(256), 0, stream, x, W, he, n);
    hipLaunchKernelGGL(hgcn_scatter, dim3((ne * 16 + 255) / 256),  dim3(256), 0, stream, he, ei, ew, sup, ne);
    hipLaunchKernelGGL(hgcn_final,   dim3((n * 16 + 255) / 256),   dim3(256), 0, stream, sup, out, n);
  }
}

// Round 11
// 60.977 us; speedup vs baseline: 12.0048x; 1.1163x over previous
//
#include <hip/hip_runtime.h>
#include <hip/hip_bf16.h>
#include <math.h>

#define DD 64
#define BROWS 64            // rows per bucket
#define BSH 6               // log2(BROWS)
#define MAXB 1024           // max buckets supported
#define CAPB 1536           // fixed bucket capacity (mean + >8 sigma headroom)
#define BINB 512            // bin block threads
#define BINC 3072           // edges per bin block (6 per thread)
#define LROWS 128           // rows per linear block (8 waves x 16)
typedef unsigned long long u64;
typedef unsigned int u32;
typedef unsigned short u16;
typedef __fp16 f16x2 __attribute__((ext_vector_type(2)));   // matches cvt_pkrtz/fdot2 builtin type

// ---------------------------------------------------------------------------
// K0: zero bucket cursors + spill counter (1 block; precedes linbin in-stream).
// ---------------------------------------------------------------------------
__global__ __launch_bounds__(1024) void hgcn_zero0(int* __restrict__ bcur,
                                                   int* __restrict__ nspill) {
  const int i = threadIdx.x;
  if (i < MAXB) bcur[i] = 0;
  if (i == 0) nspill[0] = 0;
}

// ---------------------------------------------------------------------------
// Fused linear+bin (disjoint inputs -> blocks co-schedule).
//
// bin (blockIdx < nbin): ONE LDS-atomic pass — hist atomicAdd returns local
// rank; (r,c,w,rank) stay in VGPRs; after per-bucket run reservation the
// write position is gp[b]+rank (no cursor pass). Overflow -> spill (safe).
//
// linear (blockIdx >= nbin): he = bf16((x @ W^T) * artanh(||x||)/||x||),
// exact telescoped logmap0(mobius_matvec). Per lane: W column as 32 packed
// f16x2 VGPRs; per row: x packed to LDS once, read broadcast (conflict-free),
// accumulate f32 via v_dot2_f32_f16.
// ---------------------------------------------------------------------------
__global__ __launch_bounds__(512) void hgcn_linbin(const float* __restrict__ x,
                                                   const float* __restrict__ W,
                                                   __hip_bfloat16* __restrict__ he,
                                                   const int* __restrict__ ei,
                                                   const float* __restrict__ ew,
                                                   int* __restrict__ bcur,
                                                   u64* __restrict__ stage,
                                                   u64* __restrict__ spill,
                                                   int* __restrict__ nspill,
                                                   int n, int ne, int nbin) {
  const int tid = threadIdx.x;
  if ((int)blockIdx.x < nbin) {
    // ------------------------------ bin ------------------------------------
    __shared__ int h[MAXB], gp[MAXB];
    h[tid] = 0; h[tid + 512] = 0;
    __syncthreads();
    const int eb = blockIdx.x * BINC;
    const int m = min(BINC, ne - eb);
    int r[6], c[6], rk[6];
    float w[6];
    int cnt = 0;
    #pragma unroll
    for (int k = 0; k < 6; ++k) {
      const int i = tid + k * BINB;
      if (i < m) {
        r[k] = ei[eb + i];
        c[k] = ei[ne + eb + i];
        w[k] = ew[eb + i];
        rk[k] = atomicAdd(&h[r[k] >> BSH], 1);   // rank within block
        cnt = k + 1;
      }
    }
    __syncthreads();
    {
      const int v0 = h[tid];
      gp[tid] = v0 ? atomicAdd(&bcur[tid], v0) : 0;
      const int v1 = h[tid + 512];
      gp[tid + 512] = v1 ? atomicAdd(&bcur[tid + 512], v1) : 0;
    }
    __syncthreads();
    for (int k = 0; k < cnt; ++k) {
      const int b = r[k] >> BSH;
      const int pos = gp[b] + rk[k];
      if (pos < CAPB) {
        stage[(size_t)b * CAPB + pos] =
            ((u64)__float_as_uint(w[k]) << 32) | ((u32)(r[k] & (BROWS - 1)) << 16) | (u32)c[k];
      } else {
        const int sp = atomicAdd(nspill, 1);
        spill[sp] = ((u64)__float_as_uint(w[k]) << 32) | ((u32)(r[k] & 0xffff) << 16) | (u32)c[k];
      }
    }
  } else {
    // ----------------------------- linear ----------------------------------
    __shared__ f16x2 xsh[8][32];
    const int lb = (int)blockIdx.x - nbin;
    const int wave = tid >> 6, lane = tid & 63;
    // W column `lane` as packed f16 pairs (32 VGPRs)
    f16x2 Wh[32];
    #pragma unroll
    for (int m4 = 0; m4 < 16; ++m4) {
      const float4 wv = *reinterpret_cast<const float4*>(W + lane * 64 + m4 * 4);
      Wh[2 * m4]     = __builtin_amdgcn_cvt_pkrtz(wv.x, wv.y);
      Wh[2 * m4 + 1] = __builtin_amdgcn_cvt_pkrtz(wv.z, wv.w);
    }
    const int rbase = lb * LROWS + wave * 16;
    for (int q = 0; q < 16; ++q) {
      const int row = rbase + q;
      if (row >= n) break;                        // uniform per wave
      const float xv = x[(size_t)row * DD + lane];
      float nx2 = xv * xv;
      #pragma unroll
      for (int mm = 1; mm < 64; mm <<= 1) nx2 += __shfl_xor(nx2, mm);
      const float nx = fmaxf(sqrtf(nx2), 1e-15f);
      const float z  = fminf(nx, 1.f - 1e-7f);
      const float s  = 0.5f * __logf((1.f + z) / (1.f - z)) / nx;
      // pack this row's x to LDS (even lanes write pair (x[l], x[l+1]))
      const float xo = __shfl_xor(xv, 1);
      if (!(lane & 1)) xsh[wave][lane >> 1] = __builtin_amdgcn_cvt_pkrtz(xv, xo);
      // same-wave ds ordering; compiler inserts lgkmcnt wait
      float acc = 0.f;
      #pragma unroll
      for (int m2 = 0; m2 < 32; ++m2)
        acc = __builtin_amdgcn_fdot2(xsh[wave][m2], Wh[m2], acc, false);
      he[(size_t)row * DD + lane] = __float2bfloat16(acc * s);
    }
  }
}

// ---------------------------------------------------------------------------
// Bucket aggregate + fused epilogue (NO fp atomics).
//  - stage chunk copied to LDS once; hist/scan/permute all in LDS
//  - 64 rows x 16 lanes; 2 edge-slots x 8 lanes per row, stride-2 walk with
//    1-deep prefetch; slot merge via shfl_xor(8); spill-scan (normally empty);
//    out = proj(expmap0(relu(acc))), direct coalesced store.
// ---------------------------------------------------------------------------
__global__ __launch_bounds__(1024) void hgcn_bagg(const u16* __restrict__ he,
                                                  const u64* __restrict__ stage,
                                                  const int* __restrict__ bcur,
                                                  const u64* __restrict__ spill,
                                                  const int* __restrict__ nspill,
                                                  float* __restrict__ out, int n) {
  __shared__ u64 edr[CAPB];
  __shared__ u64 ed[CAPB];
  __shared__ int lh[BROWS + 1];
  __shared__ int lcur[BROWS];
  const int t = threadIdx.x;
  const int b = blockIdx.x;
  const u64* sb = stage + (size_t)b * CAPB;
  const int cnt = min(bcur[b], CAPB);

  for (int i = t; i < cnt; i += 1024) edr[i] = sb[i];   // single global read
  if (t < BROWS) lcur[t] = 0;
  __syncthreads();
  for (int i = t; i < cnt; i += 1024)
    atomicAdd(&lcur[(int)((edr[i] >> 16) & (BROWS - 1))], 1);
  __syncthreads();
  if (t < 64) {
    const int v = lcur[t];
    int sc = v;
    #pragma unroll
    for (int d = 1; d < 64; d <<= 1) {
      const int u2 = __shfl_up(sc, d);
      if (t >= d) sc += u2;
    }
    lh[t] = sc - v;
    lcur[t] = sc - v;
    if (t == 63) lh[64] = sc;
  }
  __syncthreads();
  for (int i = t; i < cnt; i += 1024) {
    const u64 p = edr[i];
    const int rl = (int)((p >> 16) & (BROWS - 1));
    const int pos = atomicAdd(&lcur[rl], 1);
    ed[pos] = p;
  }
  __syncthreads();

  const int row = t >> 4;          // 0..63
  const int u = t & 15;
  const int s = u >> 3;            // slot 0/1
  const int l = u & 7;             // 8 lanes split D=64 as 8x8
  float a[8] = {0.f, 0.f, 0.f, 0.f, 0.f, 0.f, 0.f, 0.f};

  int j = lh[row] + s;
  const int je = lh[row + 1];
  uint4 q = {0, 0, 0, 0};
  float w = 0.f;
  if (j < je) {
    const u64 p = ed[j];
    w = __uint_as_float((u32)(p >> 32));
    q = reinterpret_cast<const uint4*>(he + ((size_t)(p & 0xffffu) << 6))[l];
  }
  while (j < je) {
    const uint4 qc = q;
    const float wc = w;
    const int jn = j + 2;
    if (jn < je) {
      const u64 p = ed[jn];
      w = __uint_as_float((u32)(p >> 32));
      q = reinterpret_cast<const uint4*>(he + ((size_t)(p & 0xffffu) << 6))[l];
    }
    a[0] = fmaf(wc, __uint_as_float(qc.x << 16), a[0]);
    a[1] = fmaf(wc, __uint_as_float(qc.x & 0xffff0000u), a[1]);
    a[2] = fmaf(wc, __uint_as_float(qc.y << 16), a[2]);
    a[3] = fmaf(wc, __uint_as_float(qc.y & 0xffff0000u), a[3]);
    a[4] = fmaf(wc, __uint_as_float(qc.z << 16), a[4]);
    a[5] = fmaf(wc, __uint_as_float(qc.z & 0xffff0000u), a[5]);
    a[6] = fmaf(wc, __uint_as_float(qc.w << 16), a[6]);
    a[7] = fmaf(wc, __uint_as_float(qc.w & 0xffff0000u), a[7]);
    j = jn;
  }

  // spill-scan: normally nspill == 0 -> one scalar load + skip. Slot 0 only.
  const int ns = nspill[0];
  for (int sidx = 0; sidx < ns; ++sidx) {
    const u64 p = spill[sidx];
    const int grow = (int)((p >> 16) & 0xffffu);
    if ((grow >> BSH) != b) continue;
    if ((grow & (BROWS - 1)) != row || s != 0) continue;
    const float ww = __uint_as_float((u32)(p >> 32));
    const uint4 qq = reinterpret_cast<const uint4*>(he + ((size_t)(p & 0xffffu) << 6))[l];
    a[0] = fmaf(ww, __uint_as_float(qq.x << 16), a[0]);
    a[1] = fmaf(ww, __uint_as_float(qq.x & 0xffff0000u), a[1]);
    a[2] = fmaf(ww, __uint_as_float(qq.y << 16), a[2]);
    a[3] = fmaf(ww, __uint_as_float(qq.y & 0xffff0000u), a[3]);
    a[4] = fmaf(ww, __uint_as_float(qq.z << 16), a[4]);
    a[5] = fmaf(ww, __uint_as_float(qq.z & 0xffff0000u), a[5]);
    a[6] = fmaf(ww, __uint_as_float(qq.w << 16), a[6]);
    a[7] = fmaf(ww, __uint_as_float(qq.w & 0xffff0000u), a[7]);
  }

  // merge the two slots (lanes u and u^8 hold the partials)
  #pragma unroll
  for (int k = 0; k < 8; ++k) a[k] += __shfl_xor(a[k], 8);

  // epilogue: out = proj(expmap0(relu(acc)))  (8-lane reduce for the norm)
  float ss = 0.f;
  #pragma unroll
  for (int k = 0; k < 8; ++k) { a[k] = fmaxf(a[k], 0.f); ss = fmaf(a[k], a[k], ss); }
  ss += __shfl_xor(ss, 1); ss += __shfl_xor(ss, 2); ss += __shfl_xor(ss, 4);
  const float nu = fmaxf(sqrtf(ss), 1e-15f);
  const float th = tanhf(nu);
  const float maxn = 1.0f - 4e-3f;
  const float scale = (th > maxn) ? (maxn / nu) : (th / nu);
  const int grow = (b << BSH) + row;
  if (s == 0 && grow < n) {
    float4* op = reinterpret_cast<float4*>(out + (size_t)grow * DD + (size_t)l * 8);
    op[0] = float4{a[0] * scale, a[1] * scale, a[2] * scale, a[3] * scale};
    op[1] = float4{a[4] * scale, a[5] * scale, a[6] * scale, a[7] * scale};
  }
}

// ---------------------------------------------------------------------------
// Deep fallback (tiny ws): atomic scatter path, fp32.
// ---------------------------------------------------------------------------
__global__ __launch_bounds__(256) void hgcn_linf32(const float* __restrict__ x,
                                                   const float* __restrict__ W,
                                                   float* __restrict__ he, int n) {
  __shared__ float Wl[64][68];
  __shared__ float xs[4][64];
  const int tid = threadIdx.x;
  for (int i = tid; i < 64 * 64; i += 256) Wl[i >> 6][i & 63] = W[i];
  const int wave = tid >> 6, lane = tid & 63;
  const int row = blockIdx.x * 4 + wave;
  float xv = 0.f;
  if (row < n) xv = x[row * DD + lane];
  xs[wave][lane] = xv;
  __syncthreads();
  if (row >= n) return;
  float nx2 = xv * xv;
  #pragma unroll
  for (int m = 1; m < 64; m <<= 1) nx2 += __shfl_xor(nx2, m);
  const float nx = fmaxf(sqrtf(nx2), 1e-15f);
  const float s = atanhf(fminf(nx, 1.f - 1e-7f)) / nx;
  const int j0 = (lane >> 3) & 7;
  float acc = 0.f;
  #pragma unroll
  for (int jj = 0; jj < 16; ++jj) {
    const int k = ((jj + j0) & 15) << 2;
    const float4 xk = *reinterpret_cast<const float4*>(&xs[wave][k]);
    const float4 wk = *reinterpret_cast<const float4*>(&Wl[lane][k]);
    acc = fmaf(xk.x, wk.x, acc); acc = fmaf(xk.y, wk.y, acc);
    acc = fmaf(xk.z, wk.z, acc); acc = fmaf(xk.w, wk.w, acc);
  }
  he[row * DD + lane] = acc * s;
}

__global__ __launch_bounds__(256) void hgcn_zero(float* __restrict__ p, int n4) {
  const int i = blockIdx.x * 256 + threadIdx.x;
  if (i < n4) reinterpret_cast<float4*>(p)[i] = float4{0.f, 0.f, 0.f, 0.f};
}

__global__ __launch_bounds__(256) void hgcn_scatter(const float* __restrict__ he,
                                                    const int* __restrict__ ei,
                                                    const float* __restrict__ ew,
                                                    float* __restrict__ sup, int ne) {
  const int t = blockIdx.x * 256 + threadIdx.x;
  const int e = t >> 4, l = t & 15;
  if (e >= ne) return;
  const int row = ei[e];
  const int col = ei[ne + e];
  const float w = ew[e];
  const float4 v = *reinterpret_cast<const float4*>(he + (size_t)col * DD + l * 4);
  float* dst = sup + (size_t)row * DD + l * 4;
  unsafeAtomicAdd(dst + 0, w * v.x);
  unsafeAtomicAdd(dst + 1, w * v.y);
  unsafeAtomicAdd(dst + 2, w * v.z);
  unsafeAtomicAdd(dst + 3, w * v.w);
}

__global__ __launch_bounds__(256) void hgcn_final(const float* __restrict__ sup,
                                                  float* __restrict__ out, int n) {
  const int t = blockIdx.x * 256 + threadIdx.x;
  const int r = t >> 4, l = t & 15;
  if (r >= n) return;
  float4 v = *reinterpret_cast<const float4*>(sup + (size_t)r * DD + l * 4);
  v.x = fmaxf(v.x, 0.f); v.y = fmaxf(v.y, 0.f);
  v.z = fmaxf(v.z, 0.f); v.w = fmaxf(v.w, 0.f);
  float p = v.x*v.x + v.y*v.y + v.z*v.z + v.w*v.w;
  p += __shfl_xor(p, 1); p += __shfl_xor(p, 2);
  p += __shfl_xor(p, 4); p += __shfl_xor(p, 8);
  const float nu = fmaxf(sqrtf(p), 1e-15f);
  const float th = tanhf(nu);
  float scale = th / nu;
  const float maxn = 1.0f - 4e-3f;
  if (th > maxn) scale = maxn / nu;
  float4 o = {v.x*scale, v.y*scale, v.z*scale, v.w*scale};
  *reinterpret_cast<float4*>(out + (size_t)r * DD + l * 4) = o;
}

extern "C" void kernel_launch(void* const* d_in, const int* in_sizes, int n_in,
                              void* d_out, int out_size, void* d_ws, size_t ws_size,
                              hipStream_t stream) {
  const float* x  = (const float*)d_in[0];
  const float* W  = (const float*)d_in[1];
  const float* ew = (const float*)d_in[2];
  const int*   ei = (const int*)d_in[3];
  const int n  = in_sizes[0] / DD;          // 50000
  const int ne = in_sizes[2];               // 800000
  const int nb = (n + BROWS - 1) / BROWS;   // buckets (782)

  // ws layout (16B-aligned blocks)
  size_t off_he    = 0;
  size_t off_stage = off_he + (((size_t)n * DD * 2 + 15) / 16) * 16;
  size_t off_spill = off_stage + (size_t)MAXB * CAPB * 8;
  size_t off_bcur  = off_spill + (size_t)ne * 8;
  size_t off_nsp   = off_bcur + MAXB * 4;
  size_t need      = off_nsp + 64;

  // performance guard only (overflow is correctness-safe via spill):
  const size_t mean = (size_t)ne / (size_t)nb;
  size_t sig = 1;
  while (sig * sig < mean) ++sig;           // ceil(sqrt(mean))
  const bool capOK = mean + 8 * sig <= CAPB;

  if (ws_size >= need && n <= 65535 && nb <= MAXB && capOK) {
    __hip_bfloat16* he = (__hip_bfloat16*)((char*)d_ws + off_he);
    u64* stage  = (u64*)((char*)d_ws + off_stage);
    u64* spill  = (u64*)((char*)d_ws + off_spill);
    int* bcur   = (int*)((char*)d_ws + off_bcur);
    int* nspill = (int*)((char*)d_ws + off_nsp);
    float* out  = (float*)d_out;

    const int nbin = (ne + BINC - 1) / BINC;        // 261
    const int nlin = (n + LROWS - 1) / LROWS;       // 391

    hipLaunchKernelGGL(hgcn_zero0,  dim3(1),           dim3(1024), 0, stream, bcur, nspill);
    hipLaunchKernelGGL(hgcn_linbin, dim3(nbin + nlin), dim3(512),  0, stream,
                       x, W, he, ei, ew, bcur, stage, spill, nspill, n, ne, nbin);
    hipLaunchKernelGGL(hgcn_bagg,   dim3(nb),          dim3(1024), 0, stream,
                       (const u16*)he, stage, bcur, spill, nspill, out, n);
  } else {
    float* he  = (float*)d_out;
    float* sup = (float*)d_ws;
    float* out = (float*)d_out;
    const int n4 = n * DD / 4;
    hipLaunchKernelGGL(hgcn_zero,    dim3((n4 + 255) / 256),       dim3(256), 0, stream, sup, n4);
    hipLaunchKernelGGL(hgcn_linf32,  dim3((n + 3) / 4),            dim3(256), 0, stream, x, W, he, n);
    hipLaunchKernelGGL(hgcn_scatter, dim3((ne * 16 + 255) / 256),  dim3(256), 0, stream, he, ei, ew, sup, ne);
    hipLaunchKernelGGL(hgcn_final,   dim3((n * 16 + 255) / 256),   dim3(256), 0, stream, sup, out, n);
  }
}